// Round 13
// baseline (113.930 us; speedup 1.0000x reference)
//
#include <hip/hip_runtime.h>
#include <hip/hip_bf16.h>

typedef __hip_bfloat16 bf16;
typedef float    f32x16 __attribute__((ext_vector_type(16)));
typedef __bf16   bf16x8 __attribute__((ext_vector_type(8)));
typedef unsigned uint4v __attribute__((ext_vector_type(4)));
typedef int      i32x2  __attribute__((ext_vector_type(2)));

#define N_TOK 4096
#define SCALE_L2E 0.2550348952703927f  // 32^-0.5 * log2(e), folded into q weights

__device__ __forceinline__ bf16x8 ld8(const bf16* p) { return *(const bf16x8*)p; }
__device__ __forceinline__ unsigned pack2(float a, float b) {
    unsigned short ua = __builtin_bit_cast(unsigned short, (__bf16)a);
    unsigned short ub = __builtin_bit_cast(unsigned short, (__bf16)b);
    return (unsigned)ua | ((unsigned)ub << 16);
}
__device__ __forceinline__ unsigned short f2b(float f) {
    return __builtin_bit_cast(unsigned short, (__bf16)f);
}

// ---------------------------------------------------------------------------
// Kernel 0: convert weights to bf16 (q rows pre-scaled). 65536 elems exactly.
// ---------------------------------------------------------------------------
__global__ void wconv(const float* __restrict__ wqkv, const float* __restrict__ wout,
                      bf16* __restrict__ wq, bf16* __restrict__ wo) {
    int idx = blockIdx.x * 256 + threadIdx.x;
    if (idx < 384 * 128) {
        float sc = (idx < 128 * 128) ? SCALE_L2E : 1.0f;
        ((unsigned short*)wq)[idx] = f2b(wqkv[idx] * sc);
    } else {
        int j = idx - 384 * 128;
        ((unsigned short*)wo)[j] = f2b(wout[j]);
    }
}

// ---------------------------------------------------------------------------
// Kernel A: qkv projection via MFMA. X tile staged TRANSPOSED [tok32][c128]
// bf16 in LDS with 16B XOR swizzle (conflict-free b128 writes AND reads);
// each X fragment = ONE ds_read_b128 (was 64x ds_read_u16). One block stages
// X once for all 12 o-tiles: 4 waves x {q-head w, k-head w, v-head w}.
// grid (128, 2), block 256.
// ---------------------------------------------------------------------------
__global__ void __launch_bounds__(256)
qkv_mfma(const float* __restrict__ x, const bf16* __restrict__ wq,
         bf16* __restrict__ qt, bf16* __restrict__ kt, bf16* __restrict__ vt) {
    int tok0 = blockIdx.x * 32;
    int b    = blockIdx.y;
    __shared__ char xs[32 * 256];   // [tok][c*2B], byte = tok*256 + (cb ^ ((tok&7)<<4))
    {   // stage: thread t -> token t&31, c-group t>>5 (16 c's, stride-N coalesced)
        int tok = threadIdx.x & 31, cg = threadIdx.x >> 5;
        const float* xp = x + ((size_t)b * 128 + cg * 16) * N_TOK + tok0 + tok;
        unsigned u[8];
#pragma unroll
        for (int j = 0; j < 8; ++j)
            u[j] = pack2(xp[(size_t)(2 * j) * N_TOK], xp[(size_t)(2 * j + 1) * N_TOK]);
        int base = tok * 256, sw = (tok & 7) << 4;
        *(uint4v*)(xs + base + ((cg * 32) ^ sw))      = (uint4v){u[0], u[1], u[2], u[3]};
        *(uint4v*)(xs + base + ((cg * 32 + 16) ^ sw)) = (uint4v){u[4], u[5], u[6], u[7]};
    }
    __syncthreads();
    int lane = threadIdx.x & 63, wv = threadIdx.x >> 6;
    int i = lane & 31, hl = lane >> 5;

    bf16x8 xf[8];
#pragma unroll
    for (int kb = 0; kb < 8; ++kb)
        xf[kb] = __builtin_bit_cast(bf16x8,
            *(const uint4v*)(xs + i * 256 + ((kb * 32 + hl * 16) ^ ((i & 7) << 4))));

    // ---- q tile (o0 = wv*32) and k tile (o0 = 128+wv*32): D[tok][d] ----
#pragma unroll
    for (int qk = 0; qk < 2; ++qk) {
        int o0 = qk * 128 + wv * 32;
        const bf16* wrow = wq + (size_t)(o0 + i) * 128 + hl * 8;
        f32x16 D;
#pragma unroll
        for (int r = 0; r < 16; ++r) D[r] = 0.f;
#pragma unroll
        for (int kb = 0; kb < 8; ++kb)
            D = __builtin_amdgcn_mfma_f32_32x32x16_bf16(xf[kb], ld8(wrow + kb * 16), D, 0, 0, 0);
        bf16* base = qk ? kt : qt;
        unsigned short* dst = (unsigned short*)(base + ((size_t)(b * 4 + wv) * N_TOK + tok0) * 32);
#pragma unroll
        for (int r = 0; r < 16; ++r) {
            int tr = (r & 3) + 8 * (r >> 2) + 4 * hl;
            dst[tr * 32 + i] = f2b(D[r]);
        }
    }
    // ---- v tile (o0 = 256+wv*32): D[d][tok] ----
    {
        const bf16* wrow = wq + (size_t)(256 + wv * 32 + i) * 128 + hl * 8;
        f32x16 D;
#pragma unroll
        for (int r = 0; r < 16; ++r) D[r] = 0.f;
#pragma unroll
        for (int kb = 0; kb < 8; ++kb)
            D = __builtin_amdgcn_mfma_f32_32x32x16_bf16(ld8(wrow + kb * 16), xf[kb], D, 0, 0, 0);
        unsigned short* dst = (unsigned short*)(vt + (size_t)(b * 4 + wv) * (32 * N_TOK) + tok0);
#pragma unroll
        for (int r = 0; r < 16; ++r) {
            int dr = (r & 3) + 8 * (r >> 2) + 4 * hl;
            dst[(size_t)dr * N_TOK + i] = f2b(D[r]);
        }
    }
}

// ---------------------------------------------------------------------------
// Kernel B: MFMA flash attention (R12 structure; K/V LDS layouts now
// FRAGMENT-ORDERED: staging writes linear, fragment reads lane-linear =>
// conflict-free both sides). Block 512 thr = 2 qpairs x 4 key-quarters;
// 128-key chunks, double-buffered (32 KB), loads issued early, 1 barrier/chunk.
// grid 256 (bh = bid&7 -> XCD-locked), block 512.
// ---------------------------------------------------------------------------
#define BUF_SZ 16384          // 8 KB K + 8 KB V per buffer
#define VOFF   8192

__global__ void __launch_bounds__(512)
attn_mfma(const bf16* __restrict__ qt, const bf16* __restrict__ kt,
          const bf16* __restrict__ vt, bf16* __restrict__ ao) {
    int bid = blockIdx.x;
    int bh  = bid & 7;
    int qg  = bid >> 3;
    int tid = threadIdx.x;
    int lane = tid & 63, wv = tid >> 6;
    int qp = wv >> 2;                     // 0/1: query group of 64
    int ks = wv & 3;                      // key quarter within chunk
    int i = lane & 31, hl = lane >> 5;

    __shared__ char lds[2 * BUF_SZ];      // 32 KB

    const bf16* qb = qt + (size_t)bh * (N_TOK * 32) + (size_t)(qg * 128 + qp * 64) * 32;
    bf16x8 q1a = ld8(qb + i * 32 + hl * 8);
    bf16x8 q2a = ld8(qb + i * 32 + 16 + hl * 8);
    bf16x8 q1b = ld8(qb + (32 + i) * 32 + hl * 8);
    bf16x8 q2b = ld8(qb + (32 + i) * 32 + 16 + hl * 8);

    // staging: thread u stages K unit u and V unit u (both linear LDS writes)
    int u = tid;
    // K unit u: key = u&127, T2hl = u>>7  ->  elems key*32 + (u>>7)*8
    const bf16* ksrc = kt + (size_t)bh * (N_TOK * 32) + (u & 127) * 32 + (u >> 7) * 8;
    int kdst = u * 16;
    // V unit u: d = u&31, kg = u>>5  ->  elems d*N_TOK + kg*8 ; LDS idx kg*32+d
    const bf16* vsrc = vt + (size_t)bh * (32 * N_TOK) + (size_t)(u & 31) * N_TOK + (u >> 5) * 8;
    int vdst = VOFF + ((u >> 5) * 32 + (u & 31)) * 16;

    // fragment read byte offsets (lane-linear)
    int koff1 = (hl * 128 + ks * 32 + i) * 16;          // T=0
    int koff2 = koff1 + 4096;                           // T=1 (+256 units)
    int voff1 = VOFF + ((ks * 4 + hl) * 32 + i) * 16;   // jh=0
    int voff2 = voff1 + 1024;                           // jh=1 (+2 kg)

    f32x16 OA, OB, Z;
#pragma unroll
    for (int r = 0; r < 16; ++r) { OA[r] = 0.f; OB[r] = 0.f; Z[r] = 0.f; }
    float lA = 0.f, lB = 0.f;

    // prologue: stage chunk 0 into buf 0
    *(uint4v*)(lds + kdst) = *(const uint4v*)ksrc;
    *(uint4v*)(lds + vdst) = *(const uint4v*)vsrc;
    __syncthreads();

    for (int t = 0; t < 32; ++t) {
        int cur = t & 1;
        uint4v nk, nv;
        if (t < 31) {   // issue next chunk's loads early
            nk = *(const uint4v*)(ksrc + (size_t)(t + 1) * 128 * 32);
            nv = *(const uint4v*)(vsrc + (t + 1) * 128);
        }
        const char* B = lds + cur * BUF_SZ;
        bf16x8 ka1 = __builtin_bit_cast(bf16x8, *(const uint4v*)(B + koff1));
        bf16x8 ka2 = __builtin_bit_cast(bf16x8, *(const uint4v*)(B + koff2));
        bf16x8 va1 = __builtin_bit_cast(bf16x8, *(const uint4v*)(B + voff1));
        bf16x8 va2 = __builtin_bit_cast(bf16x8, *(const uint4v*)(B + voff2));

        f32x16 SA = __builtin_amdgcn_mfma_f32_32x32x16_bf16(ka1, q1a, Z, 0, 0, 0);
        SA = __builtin_amdgcn_mfma_f32_32x32x16_bf16(ka2, q2a, SA, 0, 0, 0);
        f32x16 SB = __builtin_amdgcn_mfma_f32_32x32x16_bf16(ka1, q1b, Z, 0, 0, 0);
        SB = __builtin_amdgcn_mfma_f32_32x32x16_bf16(ka2, q2b, SB, 0, 0, 0);

        float pA[16], pB[16];
#pragma unroll
        for (int r = 0; r < 16; ++r) { pA[r] = __builtin_amdgcn_exp2f(SA[r]); }
#pragma unroll
        for (int r = 0; r < 16; ++r) { pB[r] = __builtin_amdgcn_exp2f(SB[r]); }
#pragma unroll
        for (int r = 0; r < 16; ++r) { lA += pA[r]; lB += pB[r]; }

        {
            unsigned k0 = pack2(pA[0], pA[1]),   k1 = pack2(pA[2], pA[3]);
            unsigned k2 = pack2(pA[4], pA[5]),   k3 = pack2(pA[6], pA[7]);
            unsigned k4 = pack2(pA[8], pA[9]),   k5 = pack2(pA[10], pA[11]);
            unsigned k6 = pack2(pA[12], pA[13]), k7 = pack2(pA[14], pA[15]);
            i32x2 t1 = __builtin_amdgcn_permlane32_swap((int)k0, (int)k2, false, false);
            i32x2 t2 = __builtin_amdgcn_permlane32_swap((int)k1, (int)k3, false, false);
            i32x2 t3 = __builtin_amdgcn_permlane32_swap((int)k4, (int)k6, false, false);
            i32x2 t4 = __builtin_amdgcn_permlane32_swap((int)k5, (int)k7, false, false);
            uint4v B1u = {(unsigned)t1.x, (unsigned)t2.x, (unsigned)t1.y, (unsigned)t2.y};
            uint4v B2u = {(unsigned)t3.x, (unsigned)t4.x, (unsigned)t3.y, (unsigned)t4.y};
            OA = __builtin_amdgcn_mfma_f32_32x32x16_bf16(va1, __builtin_bit_cast(bf16x8, B1u), OA, 0, 0, 0);
            OA = __builtin_amdgcn_mfma_f32_32x32x16_bf16(va2, __builtin_bit_cast(bf16x8, B2u), OA, 0, 0, 0);
        }
        {
            unsigned k0 = pack2(pB[0], pB[1]),   k1 = pack2(pB[2], pB[3]);
            unsigned k2 = pack2(pB[4], pB[5]),   k3 = pack2(pB[6], pB[7]);
            unsigned k4 = pack2(pB[8], pB[9]),   k5 = pack2(pB[10], pB[11]);
            unsigned k6 = pack2(pB[12], pB[13]), k7 = pack2(pB[14], pB[15]);
            i32x2 t1 = __builtin_amdgcn_permlane32_swap((int)k0, (int)k2, false, false);
            i32x2 t2 = __builtin_amdgcn_permlane32_swap((int)k1, (int)k3, false, false);
            i32x2 t3 = __builtin_amdgcn_permlane32_swap((int)k4, (int)k6, false, false);
            i32x2 t4 = __builtin_amdgcn_permlane32_swap((int)k5, (int)k7, false, false);
            uint4v B1u = {(unsigned)t1.x, (unsigned)t2.x, (unsigned)t1.y, (unsigned)t2.y};
            uint4v B2u = {(unsigned)t3.x, (unsigned)t4.x, (unsigned)t3.y, (unsigned)t4.y};
            OB = __builtin_amdgcn_mfma_f32_32x32x16_bf16(va1, __builtin_bit_cast(bf16x8, B1u), OB, 0, 0, 0);
            OB = __builtin_amdgcn_mfma_f32_32x32x16_bf16(va2, __builtin_bit_cast(bf16x8, B2u), OB, 0, 0, 0);
        }

        if (t < 31) {   // publish next chunk
            char* NB = lds + (cur ^ 1) * BUF_SZ;
            *(uint4v*)(NB + kdst) = nk;
            *(uint4v*)(NB + vdst) = nv;
        }
        __syncthreads();
    }

    // ---- combine 4 key-quarter partials per qp, one qtile phase at a time ----
    lA += __shfl_xor(lA, 32);
    lB += __shfl_xor(lB, 32);
    float* fb = (float*)lds;                       // [qp2][ks3][16][64] = 24576 B
    float* ls = (float*)(lds + 24576);             // [qp2][ks3][64] = 1536 B
    unsigned short* aop = (unsigned short*)(ao + (size_t)bh * (32 * N_TOK) + qg * 128 + qp * 64);

#pragma unroll
    for (int qtl = 0; qtl < 2; ++qtl) {
        const f32x16& O = qtl ? OB : OA;
        float l = qtl ? lB : lA;
        if (ks) {
            int s = qp * 3 + ks - 1;
#pragma unroll
            for (int r = 0; r < 16; ++r) fb[(s * 16 + r) * 64 + lane] = O[r];
            ls[s * 64 + lane] = l;
        }
        __syncthreads();
        if (ks == 0) {
            int s0 = qp * 3;
            float lt = l + ls[s0 * 64 + lane] + ls[(s0 + 1) * 64 + lane] + ls[(s0 + 2) * 64 + lane];
            float inv = 1.f / lt;
#pragma unroll
            for (int r = 0; r < 16; ++r) {
                float sv = O[r] + fb[((s0) * 16 + r) * 64 + lane] +
                           fb[((s0 + 1) * 16 + r) * 64 + lane] +
                           fb[((s0 + 2) * 16 + r) * 64 + lane];
                int d = (r & 3) + 8 * (r >> 2) + 4 * hl;
                aop[(size_t)d * N_TOK + qtl * 32 + i] = f2b(sv * inv);
            }
        }
        __syncthreads();
    }
}

// ---------------------------------------------------------------------------
// Kernel C: out projection via MFMA + bias + residual. ao tile staged
// transposed [tok][c] (16 coalesced u16 loads/thread), frags = b128 reads.
// D[row=o][col=tok] -> coalesced f32 stores. grid (128, 2), block 256,
// 4 waves x 1 o-tile.
// ---------------------------------------------------------------------------
__global__ void __launch_bounds__(256)
out_mfma(const bf16* __restrict__ ao, const bf16* __restrict__ wo,
         const float* __restrict__ bias, const float* __restrict__ x,
         float* __restrict__ out) {
    int tok0 = blockIdx.x * 32;
    int b    = blockIdx.y;
    __shared__ char as[32 * 256];
    {   // stage transposed: thread t -> token t&31, c-group t>>5
        int tok = threadIdx.x & 31, cg = threadIdx.x >> 5;
        const unsigned short* ap = (const unsigned short*)ao +
            ((size_t)b * 128 + cg * 16) * N_TOK + tok0 + tok;
        unsigned u[8];
#pragma unroll
        for (int j = 0; j < 8; ++j)
            u[j] = (unsigned)ap[(size_t)(2 * j) * N_TOK] |
                   ((unsigned)ap[(size_t)(2 * j + 1) * N_TOK] << 16);
        int base = tok * 256, sw = (tok & 7) << 4;
        *(uint4v*)(as + base + ((cg * 32) ^ sw))      = (uint4v){u[0], u[1], u[2], u[3]};
        *(uint4v*)(as + base + ((cg * 32 + 16) ^ sw)) = (uint4v){u[4], u[5], u[6], u[7]};
    }
    __syncthreads();
    int lane = threadIdx.x & 63, wv = threadIdx.x >> 6;
    int i = lane & 31, hl = lane >> 5;
    int o0 = wv * 32;

    f32x16 D;
#pragma unroll
    for (int r = 0; r < 16; ++r) D[r] = 0.f;
    const bf16* wrow = wo + (size_t)(o0 + i) * 128 + hl * 8;
#pragma unroll
    for (int kb = 0; kb < 8; ++kb) {
        bf16x8 af = __builtin_bit_cast(bf16x8,
            *(const uint4v*)(as + i * 256 + ((kb * 32 + hl * 16) ^ ((i & 7) << 4))));
        D = __builtin_amdgcn_mfma_f32_32x32x16_bf16(ld8(wrow + kb * 16), af, D, 0, 0, 0);
    }

#pragma unroll
    for (int r = 0; r < 16; ++r) {
        int o_r = o0 + (r & 3) + 8 * (r >> 2) + 4 * hl;
        size_t idx = ((size_t)b * 128 + o_r) * N_TOK + tok0 + i;
        out[idx] = D[r] + bias[o_r] + x[idx];
    }
}

// ---------------------------------------------------------------------------
extern "C" void kernel_launch(void* const* d_in, const int* in_sizes, int n_in,
                              void* d_out, int out_size, void* d_ws, size_t ws_size,
                              hipStream_t stream) {
    const float* x     = (const float*)d_in[0];
    const float* w_qkv = (const float*)d_in[1];
    const float* w_out = (const float*)d_in[2];
    const float* b_out = (const float*)d_in[3];
    float* out = (float*)d_out;

    bf16* qt = (bf16*)d_ws;                          // [8][4096][32] bf16 = 2 MB
    bf16* kt = qt + (size_t)8 * N_TOK * 32;          // [8][4096][32] bf16 = 2 MB
    bf16* vt = kt + (size_t)8 * N_TOK * 32;          // [8][32][4096] bf16 = 2 MB
    bf16* ao = vt + (size_t)8 * N_TOK * 32;          // [2][128][4096] bf16 = 2 MB
    bf16* wq = ao + (size_t)2 * 128 * N_TOK;         // [384][128] bf16
    bf16* wo = wq + (size_t)384 * 128;               // [128][128] bf16

    wconv    <<<dim3(256), 256, 0, stream>>>(w_qkv, w_out, wq, wo);
    qkv_mfma <<<dim3(128, 2), 256, 0, stream>>>(x, wq, qt, kt, vt);
    attn_mfma<<<dim3(256), 512, 0, stream>>>(qt, kt, vt, ao);
    out_mfma <<<dim3(128, 2), 256, 0, stream>>>(ao, wo, b_out, x, out);
}